// Round 9
// baseline (31448.575 us; speedup 1.0000x reference)
//
#include <hip/hip_runtime.h>
#include <math.h>

#define TOPK 100
#define HW 65536                   // 256*256
#define SLICE_STRIDE (7*HW)        // 458752
#define NBATCH 32
#define NBOX 200
#define HM (3*HW)                  // 196608 heatmap elems per slice

// Literal mechanical port of the reference. One block per batch, 256 threads.
// Top-k: 100 block-wide argmax passes with an LDS selected-bitmask (exact
// lax.top_k semantics incl. lowest-index ties, no distribution assumptions).
// Soft-NMS: literal transcription with physical row swaps in LDS.
__global__ __launch_bounds__(256) void kref(const float* __restrict__ x,
                                            float* __restrict__ out) {
    __shared__ float rv[256];
    __shared__ int   ri[256];
    __shared__ unsigned selmask[HM / 32];   // 6144 words = 24 KB
    __shared__ float bxs[NBOX][4];
    __shared__ float scs[NBOX];
    __shared__ float cl[NBOX];

    int b = blockIdx.x, t = threadIdx.x;

    // ---- per-slice exact top-100 + decode ----
    for (int s = 0; s < 2; ++s) {
        const float* xb = x + (size_t)(2 * b + s) * SLICE_STRIDE;
        for (int i = t; i < HM / 32; i += 256) selmask[i] = 0;
        __syncthreads();
        for (int r = 0; r < TOPK; ++r) {
            // argmax over unselected raw logits (monotone with sigmoid;
            // equal z <=> equal sigmoid, so tie sets are identical)
            float bv = -INFINITY; int bi = 0x7FFFFFFF;
            for (int i = t; i < HM; i += 256) {
                if (!((selmask[i >> 5] >> (i & 31)) & 1u)) {
                    float v = xb[i];
                    if (v > bv || (v == bv && i < bi)) { bv = v; bi = i; }
                }
            }
            rv[t] = bv; ri[t] = bi;
            __syncthreads();
            for (int off = 128; off > 0; off >>= 1) {
                if (t < off) {
                    float ov = rv[t + off]; int oi = ri[t + off];
                    if (ov > rv[t] || (ov == rv[t] && oi < ri[t])) { rv[t] = ov; ri[t] = oi; }
                }
                __syncthreads();
            }
            if (t == 0) {
                int w = ri[0];
                selmask[w >> 5] |= (1u << (w & 31));
                float z = rv[0];
                int c = w / HW;
                int rem = w - c * HW;
                float ysf = (float)(rem >> 8);      // ys = rem // W
                float xsf = (float)(rem & 255);     // xs = rem % W
                float offx = xb[3 * HW + rem];
                float offy = xb[4 * HW + rem];
                float bw = xb[5 * HW + rem] * 4.0f;
                float bh = xb[6 * HW + rem] * 4.0f;
                float cx = (xsf + offx) * 4.0f;
                float cy = (ysf + offy) * 4.0f;
                int slot = s * TOPK + r;
                bxs[slot][0] = cx - bw * 0.5f;
                bxs[slot][1] = cy - bh * 0.5f;
                bxs[slot][2] = cx + bw * 0.5f;
                bxs[slot][3] = cy + bh * 0.5f;
                float sg = 1.0f / (1.0f + expf(-z));
                scs[slot] = (sg > 0.1f) ? sg : 0.0f;
                cl[slot] = (float)c;
            }
            __syncthreads();
        }
    }

    // ---- literal soft-NMS: argmax (first occurrence) + swap + decay ----
    for (int i = 0; i < NBOX; ++i) {
        float bv = -INFINITY; int bp = 0x7FFFFFFF;
        for (int p = i + t; p < NBOX; p += 256) {
            float v = scs[p];
            if (v > bv || (v == bv && p < bp)) { bv = v; bp = p; }
        }
        rv[t] = bv; ri[t] = bp;
        __syncthreads();
        for (int off = 128; off > 0; off >>= 1) {
            if (t < off) {
                float ov = rv[t + off]; int oi = ri[t + off];
                if (ov > rv[t] || (ov == rv[t] && oi < ri[t])) { rv[t] = ov; ri[t] = oi; }
            }
            __syncthreads();
        }
        int m = ri[0];
        if (t == 0 && m != i) {
            for (int k = 0; k < 4; ++k) {
                float tmp = bxs[i][k]; bxs[i][k] = bxs[m][k]; bxs[m][k] = tmp;
            }
            float ts = scs[i]; scs[i] = scs[m]; scs[m] = ts;
            float tc = cl[i]; cl[i] = cl[m]; cl[m] = tc;
        }
        __syncthreads();
        float b0 = bxs[i][0], b1 = bxs[i][1], b2 = bxs[i][2], b3 = bxs[i][3];
        float area_i = (b2 - b0 + 1.0f) * (b3 - b1 + 1.0f);
        for (int p = i + 1 + t; p < NBOX; p += 256) {
            float x1 = bxs[p][0], y1 = bxs[p][1], x2 = bxs[p][2], y2 = bxs[p][3];
            float areas = (x2 - x1 + 1.0f) * (y2 - y1 + 1.0f);
            float xx1 = fmaxf(b0, x1);
            float yy1 = fmaxf(b1, y1);
            float xx2 = fminf(b2, x2);
            float yy2 = fminf(b3, y2);
            float inter = fmaxf(0.0f, xx2 - xx1 + 1.0f) * fmaxf(0.0f, yy2 - yy1 + 1.0f);
            float iou = inter / (area_i + areas - inter);
            float w = expf(-(iou * iou) / 0.5f);
            scs[p] = w * scs[p];
        }
        __syncthreads();
    }

    // ---- write outputs [boxes, cls, scores, keep] ----
    float* ob = out + (size_t)b * NBOX * 4;
    float* oc = out + (size_t)NBATCH * NBOX * 4 + b * NBOX;
    float* os = out + (size_t)NBATCH * NBOX * 5 + b * NBOX;
    float* okp = out + (size_t)NBATCH * NBOX * 6 + b * NBOX;
    for (int p = t; p < NBOX; p += 256) {
        ob[p * 4 + 0] = bxs[p][0];
        ob[p * 4 + 1] = bxs[p][1];
        ob[p * 4 + 2] = bxs[p][2];
        ob[p * 4 + 3] = bxs[p][3];
        oc[p] = cl[p];
        os[p] = scs[p];
        okp[p] = (scs[p] > 0.1f) ? 1.0f : 0.0f;
    }
}

extern "C" void kernel_launch(void* const* d_in, const int* in_sizes, int n_in,
                              void* d_out, int out_size, void* d_ws, size_t ws_size,
                              hipStream_t stream) {
    const float* x = (const float*)d_in[0];
    float* out = (float*)d_out;
    kref<<<NBATCH, 256, 0, stream>>>(x, out);
}